// Round 12
// baseline (850.580 us; speedup 1.0000x reference)
//
#include <hip/hip_runtime.h>
#include <stdint.h>

#define LSEQ 64
#define BATCH 2048
#define HID 512
#define NG 2048          // 4*HID gate rows (permuted: n = 4*j + q)
#define KP 576           // 512 + 64 (E=50 padded to 64)
#define VOCAB 96
#define BH (BATCH*HID)   // 1048576

// LDS map for k_persist (dynamic, 139264 B):
//   Wlds : 8 tiles (kt=0..7) x 16KB @ 0       (persistent, read-only after init)
//   hpk  : [128 b][32 u] u16 swizzled @ 131072
#define WLDS_OFF 0
#define HPK_OFF  131072
#define SMEM_TOT 139264

typedef unsigned short u16;
typedef __attribute__((ext_vector_type(8))) short short8;
typedef __attribute__((ext_vector_type(4))) float f32x4;

__device__ __forceinline__ u16 f2bf(float f) {
    union { float f; unsigned u; } v; v.f = f;
    return (u16)((v.u + 0x7FFFu + ((v.u >> 16) & 1u)) >> 16);   // RNE
}
__device__ __forceinline__ float sig_(float x) { return 1.f / (1.f + __expf(-x)); }
__device__ __forceinline__ float th_(float x) {
    x = fminf(fmaxf(x, -30.f), 30.f);
    float e = __expf(2.f * x);
    return (e - 1.f) / (e + 1.f);
}
__device__ __forceinline__ void gld16(const void* g, void* l) {
    __builtin_amdgcn_global_load_lds(
        (const __attribute__((address_space(1))) unsigned int*)g,
        (__attribute__((address_space(3))) unsigned int*)l, 16, 0, 0);
}
#define WAITV(n) asm volatile("s_waitcnt vmcnt(" #n ")" ::: "memory")

// ---------------- prep kernels ----------------
__global__ void k_init(const float* __restrict__ h0, u16* __restrict__ hs0,
                       unsigned* __restrict__ flags) {
    int i = blockIdx.x * 256 + threadIdx.x;       // BH threads exactly
    hs0[i] = f2bf(h0[i]);
    if (i < LSEQ * 256) flags[i] = 0;             // re-zero sync flags every launch
}

// Wp[n][k], n = 4*j+q -> src row q*512+j of [W_hh | W_ih | pad]; bias fused.
__global__ void k_pack_w(const float* __restrict__ Wih, const float* __restrict__ Whh,
                         const float* __restrict__ bih, const float* __restrict__ bhh,
                         u16* __restrict__ Wp, float* __restrict__ bp) {
    int id = blockIdx.x * 256 + threadIdx.x;      // NG*72 threads exactly
    int n = id / 72, kc = id % 72;
    int j = n >> 2, q = n & 3;
    int src = q * HID + j;
    int k0 = kc * 8;
    unsigned pk[4];
#pragma unroll
    for (int t = 0; t < 4; ++t) {
        int k = k0 + 2 * t;
        float f0 = (k < 512) ? Whh[src * 512 + k] : ((k < 562) ? Wih[src * 50 + k - 512] : 0.f);
        float f1 = (k + 1 < 512) ? Whh[src * 512 + k + 1]
                                 : ((k + 1 < 562) ? Wih[src * 50 + k + 1 - 512] : 0.f);
        pk[t] = (unsigned)f2bf(f0) | ((unsigned)f2bf(f1) << 16);
    }
    *(uint4*)(Wp + (size_t)n * KP + k0) = make_uint4(pk[0], pk[1], pk[2], pk[3]);
    if (kc == 0) bp[n] = bih[src] + bhh[src];
}

// x_bf16[l*B + b][64]: emb[ids[l,b], 0:50], zero-padded to 64
__global__ void k_embed(const int* __restrict__ ids, const float* __restrict__ emb,
                        u16* __restrict__ xb) {
    int id = blockIdx.x * 256 + threadIdx.x;      // LSEQ*BATCH*8 threads exactly
    int row = id >> 3, kc = id & 7;
    int tok = ids[row];
    int k0 = kc * 8;
    unsigned pk[4];
#pragma unroll
    for (int t = 0; t < 4; ++t) {
        int k = k0 + 2 * t;
        unsigned lo = (k < 50) ? (unsigned)f2bf(emb[tok * 50 + k]) : 0u;
        unsigned hi = (k + 1 < 50) ? (unsigned)f2bf(emb[tok * 50 + k + 1]) : 0u;
        pk[t] = lo | (hi << 16);
    }
    *(uint4*)(xb + (size_t)row * 64 + k0) = make_uint4(pk[0], pk[1], pk[2], pk[3]);
}

__global__ void k_pack_wout(const float* __restrict__ Wo, u16* __restrict__ Wb) {
    int id = blockIdx.x * 256 + threadIdx.x;      // VOCAB*HID/8 = 6144 threads
    int k0 = id * 8;
    unsigned pk[4];
#pragma unroll
    for (int t = 0; t < 4; ++t)
        pk[t] = (unsigned)f2bf(Wo[k0 + 2 * t]) | ((unsigned)f2bf(Wo[k0 + 2 * t + 1]) << 16);
    *(uint4*)(Wb + k0) = make_uint4(pk[0], pk[1], pk[2], pk[3]);
}

// ---------------- persistent LSTM: reg-staged h, barrier-free GEMM ----------
// 256 blocks = 1/CU. Block = 128 batch rows (bm) x 128 gate cols (bn); all
// producers/consumers of row-group bm share XCD bm%8 -> h exchange is L2-local.
// h MFMA fragments are loaded DIRECTLY global->VGPR (T14): no LDS staging for
// h, no barriers in the K-loop — per-wave counted vmcnt(8), 2-deep frag dbuf.
// W: x-slice in 32 VGPRs; kt0..7 persistent in LDS (read-only after init).
// D = W x h: lane's acc[qm][qn] = (i,f,g,o) of one (batch,unit); cell in regs.
__global__ __launch_bounds__(256, 1) void k_persist(
    const u16* __restrict__ xb, const u16* __restrict__ Wp,
    const float* __restrict__ bp, const float* __restrict__ c0,
    u16* __restrict__ hs, float* __restrict__ foutH, float* __restrict__ foutC,
    unsigned* __restrict__ flags)
{
    extern __shared__ char smem[];
    char* Wlds = smem + WLDS_OFF;
    u16*  hpk  = (u16*)(smem + HPK_OFF);

    const int tid = threadIdx.x;
    const int lane = tid & 63;
    const int w = tid >> 6;
    const int wm = w >> 1, wn = w & 1;          // wm: gate half, wn: batch half
    const int bm = blockIdx.x & 15, bn = blockIdx.x >> 4;
    const int m0 = bm * 128, n0 = bn * 128;
    const int rsub = lane >> 3;
    const int colsw = (((lane & 7) ^ rsub) << 3);   // W staging swizzle (u16 units)
    const int bsub = lane & 15;
    const int usub = lane >> 4;                 // 0..3
    const int brow = m0 + wn * 64 + bsub;       // batch row base (qn adds 16)

    // ---- stage W K-tiles kt=0..7 into LDS (once, read-only afterwards) ----
#pragma unroll
    for (int t = 0; t < 8; ++t)
#pragma unroll
        for (int it = 0; it < 4; ++it) {
            int wc = w * 4 + it;
            gld16(Wp + (size_t)(n0 + wc * 8 + rsub) * KP + t * 64 + colsw,
                  Wlds + t * 16384 + wc * 1024);
        }

    // ---- W x-slice (k=512..575) in regs: 8 short8 = 32 VGPR ----
    short8 wrx[2][4];
#pragma unroll
    for (int kk = 0; kk < 2; ++kk)
#pragma unroll
        for (int qm = 0; qm < 4; ++qm)
            wrx[kk][qm] = *(const short8*)(
                Wp + (size_t)(n0 + wm * 64 + qm * 16 + bsub) * KP
                   + 512 + kk * 32 + usub * 8);

    // ---- bias (i,f,g,o per unit) + resident c-state ----
    float4 bb[4];
#pragma unroll
    for (int qm = 0; qm < 4; ++qm)
        bb[qm] = *(const float4*)(bp + n0 + wm * 64 + qm * 16 + usub * 4);
    float c[4][4];
#pragma unroll
    for (int qm = 0; qm < 4; ++qm)
#pragma unroll
        for (int qn = 0; qn < 4; ++qn)
            c[qm][qn] = c0[(size_t)(brow + qn * 16) * HID
                           + (n0 >> 2) + wm * 16 + qm * 4 + usub];

    WAITV(0);
    __syncthreads();                            // Wlds ready for all waves

    short8 pA[8], pB[8];                        // frag dbuf: [kk*4+qn]

#pragma unroll 1
    for (int l = 0; l < LSEQ; ++l) {
        const u16* hsrc = hs + (size_t)l * BH;
        const u16* xsrc = xb + (size_t)l * BATCH * 64;

        // issue x frags (phase 0) BEFORE the spin — covers poll latency
#pragma unroll
        for (int kk = 0; kk < 2; ++kk)
#pragma unroll
            for (int qn = 0; qn < 4; ++qn)
                pA[kk * 4 + qn] = *(const short8*)(
                    xsrc + (size_t)(brow + qn * 16) * 64 + kk * 32 + usub * 8);

        if (l > 0 && w == 0) {                  // wait step-(l-1) producers of row bm
            const unsigned* f = flags + (unsigned)(l - 1) * 256 + bm * 16;
            for (;;) {
                unsigned v = (lane < 16)
                    ? __hip_atomic_load(f + lane, __ATOMIC_RELAXED, __HIP_MEMORY_SCOPE_AGENT)
                    : 1u;
                if (__all(v != 0)) break;
                __builtin_amdgcn_s_sleep(2);
            }
        }
        __syncthreads();                        // ordering: h loads must not pass flags
        __builtin_amdgcn_sched_barrier(0);

        // issue P1 = h kt0 frags
#pragma unroll
        for (int kk = 0; kk < 2; ++kk)
#pragma unroll
            for (int qn = 0; qn < 4; ++qn)
                pB[kk * 4 + qn] = *(const short8*)(
                    hsrc + (size_t)(brow + qn * 16) * HID + kk * 32 + usub * 8);

        f32x4 acc[4][4] = {};
        // barrier-free K-loop: phase i consumes p[i&1], refills with P(i+2)
#pragma unroll
        for (int i = 0; i < 9; ++i) {
            if (i < 8) WAITV(8); else WAITV(0);
            __builtin_amdgcn_sched_barrier(0);
            short8* cur = (i & 1) ? pB : pA;
#pragma unroll
            for (int kk = 0; kk < 2; ++kk) {
                short8 wf[4];
                if (i == 0) {
#pragma unroll
                    for (int qm = 0; qm < 4; ++qm) wf[qm] = wrx[kk][qm];
                } else {
                    const u16* Ws_ = (const u16*)(Wlds + (i - 1) * 16384);
#pragma unroll
                    for (int qm = 0; qm < 4; ++qm)
                        wf[qm] = *(const short8*)(Ws_ + (wm * 64 + qm * 16 + bsub) * 64
                                     + (((kk * 4 + usub) ^ (lane & 7)) << 3));
                }
#pragma unroll
                for (int qm = 0; qm < 4; ++qm)
#pragma unroll
                    for (int qn = 0; qn < 4; ++qn)
                        acc[qm][qn] = __builtin_amdgcn_mfma_f32_16x16x32_bf16(
                            wf[qm], cur[kk * 4 + qn], acc[qm][qn], 0, 0, 0);
            }
            __builtin_amdgcn_sched_barrier(0);
            if (i + 2 <= 8) {                   // refill cur with h kt=i+1
#pragma unroll
                for (int kk = 0; kk < 2; ++kk)
#pragma unroll
                    for (int qn = 0; qn < 4; ++qn)
                        cur[kk * 4 + qn] = *(const short8*)(
                            hsrc + (size_t)(brow + qn * 16) * HID
                                 + (i + 1) * 64 + kk * 32 + usub * 8);
            }
        }

        // cell fully in-register: acc[qm][qn] = (i,f,g,o) of (batch b, unit u)
        const bool last = (l == LSEQ - 1);
#pragma unroll
        for (int qm = 0; qm < 4; ++qm) {
            const float4 b4 = bb[qm];
            const int u_loc = wm * 16 + qm * 4 + usub;
#pragma unroll
            for (int qn = 0; qn < 4; ++qn) {
                const int b_loc = wn * 64 + qn * 16 + bsub;
                float gi = acc[qm][qn][0] + b4.x;
                float gf = acc[qm][qn][1] + b4.y;
                float gg = acc[qm][qn][2] + b4.z;
                float go = acc[qm][qn][3] + b4.w;
                float cn = sig_(gf) * c[qm][qn] + sig_(gi) * th_(gg);
                float hn = sig_(go) * th_(cn);
                c[qm][qn] = cn;
                hpk[b_loc * 32 + (u_loc ^ ((b_loc & 7) << 2))] = f2bf(hn);
                if (last) {
                    size_t ci = (size_t)(m0 + b_loc) * HID + (n0 >> 2) + u_loc;
                    foutH[ci] = hn; foutC[ci] = cn;
                }
            }
        }
        __syncthreads();                        // hpack complete

        // coalesced h store: thread -> 32B of hs[l+1] (same-XCD L2 exchange)
        {
            const int b = tid >> 1, hf = tid & 1;
            unsigned long long q[4];
#pragma unroll
            for (int g = 0; g < 4; ++g) {
                int G = hf * 4 + g;
                int gs = G ^ (b & 7);
                q[g] = *(const unsigned long long*)((const char*)hpk + b * 64 + gs * 8);
            }
            u16* dst = hs + (size_t)(l + 1) * BH + (size_t)(m0 + b) * HID
                       + (n0 >> 2) + hf * 16;
            *(uint4*)(dst)     = make_uint4((unsigned)q[0], (unsigned)(q[0] >> 32),
                                            (unsigned)q[1], (unsigned)(q[1] >> 32));
            *(uint4*)(dst + 8) = make_uint4((unsigned)q[2], (unsigned)(q[2] >> 32),
                                            (unsigned)q[3], (unsigned)(q[3] >> 32));
        }
        WAITV(0);                               // h (and last-step fout) stores in L2
        __syncthreads();                        // every wave's stores drained
        if (tid == 0)
            __hip_atomic_store(flags + (unsigned)l * 256 + bm * 16 + bn, 1u,
                               __ATOMIC_RELAXED, __HIP_MEMORY_SCOPE_AGENT);
    }
}

// ---------------- output projection: (L*B, 512) x (96, 512)^T ----------------
__global__ __launch_bounds__(256) void k_scores(
    const u16* __restrict__ hsall, const u16* __restrict__ Wb,
    const float* __restrict__ bo, float* __restrict__ out)
{
    __shared__ char smem[28672];
    u16* As = (u16*)smem;               // [128][64]
    u16* Bs = (u16*)(smem + 16384);     // [96][64]
    const int tid = threadIdx.x, lane = tid & 63, w = tid >> 6;
    const size_t m0 = (size_t)blockIdx.x * 128;
    const int colo = (lane & 7) * 8;
    const int rsub = lane >> 3;
    f32x4 acc[2][6] = {};

    for (int kt = 0; kt < 8; ++kt) {
#pragma unroll
        for (int it = 0; it < 4; ++it) {
            int wc = w * 4 + it;
            int r = wc * 8 + rsub;
            gld16(hsall + (m0 + r) * 512 + kt * 64 + colo, smem + wc * 1024);
        }
#pragma unroll
        for (int it = 0; it < 3; ++it) {
            int wc = w * 3 + it;                  // 0..11
            int r = wc * 8 + rsub;                // 0..95
            gld16(Wb + (size_t)r * 512 + kt * 64 + colo, smem + 16384 + wc * 1024);
        }
        __syncthreads();
#pragma unroll
        for (int kk = 0; kk < 2; ++kk) {
            short8 av[2], bv[6];
#pragma unroll
            for (int i = 0; i < 2; ++i)
                av[i] = *(const short8*)(As + (w * 32 + i * 16 + (lane & 15)) * 64 + kk * 32 + (lane >> 4) * 8);
#pragma unroll
            for (int j = 0; j < 6; ++j)
                bv[j] = *(const short8*)(Bs + (j * 16 + (lane & 15)) * 64 + kk * 32 + (lane >> 4) * 8);
#pragma unroll
            for (int i = 0; i < 2; ++i)
#pragma unroll
                for (int j = 0; j < 6; ++j)
                    acc[i][j] = __builtin_amdgcn_mfma_f32_16x16x32_bf16(av[i], bv[j], acc[i][j], 0, 0, 0);
        }
        __syncthreads();
    }
#pragma unroll
    for (int i = 0; i < 2; ++i) {
        int ml = w * 32 + i * 16 + (lane >> 4) * 4;
#pragma unroll
        for (int j = 0; j < 6; ++j) {
            int v = j * 16 + (lane & 15);
            float bbv = bo[v];
#pragma unroll
            for (int r = 0; r < 4; ++r)
                out[(m0 + ml + r) * 96 + v] = acc[i][j][r] + bbv;
        }
    }
}

// ---------------- launcher ----------------
extern "C" void kernel_launch(void* const* d_in, const int* in_sizes, int n_in,
                              void* d_out, int out_size, void* d_ws, size_t ws_size,
                              hipStream_t stream) {
    const int*   ids  = (const int*)d_in[0];
    const float* h0   = (const float*)d_in[1];
    const float* c0   = (const float*)d_in[2];
    const float* emb  = (const float*)d_in[3];
    const float* Wih  = (const float*)d_in[4];
    const float* Whh  = (const float*)d_in[5];
    const float* bih  = (const float*)d_in[6];
    const float* bhh  = (const float*)d_in[7];
    const float* Wout = (const float*)d_in[8];
    const float* bout = (const float*)d_in[9];

    char* ws = (char*)d_ws;
    u16*      hs    = (u16*)ws;                       // 65*BH*2 = 136,314,880
    unsigned* flags = (unsigned*)(ws + 136314880);    // 64*256*4
    u16*      xb    = (u16*)(ws + 140509184);         // L*B*64*2
    u16*      Wp    = (u16*)(ws + 157286400);         // 2048*576*2
    float*    bp    = (float*)(ws + 159645696);       // 2048*4
    u16*      Wb    = (u16*)(ws + 159653888);         // 96*512*2
    float*    out   = (float*)d_out;

    k_init<<<dim3(BH / 256), dim3(256), 0, stream>>>(h0, hs, flags);
    k_pack_w<<<dim3(NG * 72 / 256), dim3(256), 0, stream>>>(Wih, Whh, bih, bhh, Wp, bp);
    k_embed<<<dim3(LSEQ * BATCH * 8 / 256), dim3(256), 0, stream>>>(ids, emb, xb);
    k_pack_wout<<<dim3(VOCAB * HID / 8 / 256), dim3(256), 0, stream>>>(Wout, Wb);

    hipFuncSetAttribute((const void*)k_persist,
                        hipFuncAttributeMaxDynamicSharedMemorySize, SMEM_TOT);
    k_persist<<<dim3(256), dim3(256), SMEM_TOT, stream>>>(
        xb, Wp, bp, c0, hs, out + 12582912, out + 12582912 + BH, flags);

    k_scores<<<dim3(LSEQ * BATCH / 128), dim3(256), 0, stream>>>(hs + BH, Wb, bout, out);
}

// Round 13
// 524.680 us; speedup vs baseline: 1.6211x; 1.6211x over previous
//
#include <hip/hip_runtime.h>
#include <stdint.h>

#define LSEQ 64
#define BATCH 2048
#define HID 512
#define NG 2048          // 4*HID gate rows (permuted: n = 4*j + q)
#define KP 576           // 512 + 64 (E=50 padded to 64)
#define VOCAB 96
#define BH (BATCH*HID)   // 1048576

// LDS map for k_persist (dynamic, 155648 B):
//   Wlds  : 6 tiles (kt=2..7) x 16KB   @ 0
//   ring  : 3 slots x 16KB             @ 98304
//   hpack : [128 b][32 u] u16 swizzled @ 147456
#define WLDS_OFF 0
#define RING_OFF 98304
#define HPK_OFF  147456
#define SMEM_TOT 155648

typedef unsigned short u16;
typedef __attribute__((ext_vector_type(8))) short short8;
typedef __attribute__((ext_vector_type(4))) float f32x4;

__device__ __forceinline__ u16 f2bf(float f) {
    union { float f; unsigned u; } v; v.f = f;
    return (u16)((v.u + 0x7FFFu + ((v.u >> 16) & 1u)) >> 16);   // RNE
}
__device__ __forceinline__ float sig_(float x) { return 1.f / (1.f + __expf(-x)); }
__device__ __forceinline__ float th_(float x) {
    x = fminf(fmaxf(x, -30.f), 30.f);
    float e = __expf(2.f * x);
    return (e - 1.f) / (e + 1.f);
}
__device__ __forceinline__ void gld16(const void* g, void* l) {
    __builtin_amdgcn_global_load_lds(
        (const __attribute__((address_space(1))) unsigned int*)g,
        (__attribute__((address_space(3))) unsigned int*)l, 16, 0, 0);
}
#define WAITV(n) asm volatile("s_waitcnt vmcnt(" #n ")" ::: "memory")

// ---------------- prep kernels ----------------
__global__ void k_init(const float* __restrict__ h0, u16* __restrict__ hs0,
                       unsigned* __restrict__ flags) {
    int i = blockIdx.x * 256 + threadIdx.x;       // BH threads exactly
    hs0[i] = f2bf(h0[i]);
    if (i < LSEQ * 256) flags[i] = 0;             // re-zero sync flags every launch
}

// Wp[n][k], n = 4*j+q -> src row q*512+j of [W_hh | W_ih | pad]; bias fused.
__global__ void k_pack_w(const float* __restrict__ Wih, const float* __restrict__ Whh,
                         const float* __restrict__ bih, const float* __restrict__ bhh,
                         u16* __restrict__ Wp, float* __restrict__ bp) {
    int id = blockIdx.x * 256 + threadIdx.x;      // NG*72 threads exactly
    int n = id / 72, kc = id % 72;
    int j = n >> 2, q = n & 3;
    int src = q * HID + j;
    int k0 = kc * 8;
    unsigned pk[4];
#pragma unroll
    for (int t = 0; t < 4; ++t) {
        int k = k0 + 2 * t;
        float f0 = (k < 512) ? Whh[src * 512 + k] : ((k < 562) ? Wih[src * 50 + k - 512] : 0.f);
        float f1 = (k + 1 < 512) ? Whh[src * 512 + k + 1]
                                 : ((k + 1 < 562) ? Wih[src * 50 + k + 1 - 512] : 0.f);
        pk[t] = (unsigned)f2bf(f0) | ((unsigned)f2bf(f1) << 16);
    }
    *(uint4*)(Wp + (size_t)n * KP + k0) = make_uint4(pk[0], pk[1], pk[2], pk[3]);
    if (kc == 0) bp[n] = bih[src] + bhh[src];
}

// x_bf16[l*B + b][64]: emb[ids[l,b], 0:50], zero-padded to 64
__global__ void k_embed(const int* __restrict__ ids, const float* __restrict__ emb,
                        u16* __restrict__ xb) {
    int id = blockIdx.x * 256 + threadIdx.x;      // LSEQ*BATCH*8 threads exactly
    int row = id >> 3, kc = id & 7;
    int tok = ids[row];
    int k0 = kc * 8;
    unsigned pk[4];
#pragma unroll
    for (int t = 0; t < 4; ++t) {
        int k = k0 + 2 * t;
        unsigned lo = (k < 50) ? (unsigned)f2bf(emb[tok * 50 + k]) : 0u;
        unsigned hi = (k + 1 < 50) ? (unsigned)f2bf(emb[tok * 50 + k + 1]) : 0u;
        pk[t] = lo | (hi << 16);
    }
    *(uint4*)(xb + (size_t)row * 64 + k0) = make_uint4(pk[0], pk[1], pk[2], pk[3]);
}

__global__ void k_pack_wout(const float* __restrict__ Wo, u16* __restrict__ Wb) {
    int id = blockIdx.x * 256 + threadIdx.x;      // VOCAB*HID/8 = 6144 threads
    int k0 = id * 8;
    unsigned pk[4];
#pragma unroll
    for (int t = 0; t < 4; ++t)
        pk[t] = (unsigned)f2bf(Wo[k0 + 2 * t]) | ((unsigned)f2bf(Wo[k0 + 2 * t + 1]) << 16);
    *(uint4*)(Wb + k0) = make_uint4(pk[0], pk[1], pk[2], pk[3]);
}

// ---------------- persistent LSTM: r11 structure at 8 waves (2/SIMD) --------
// 256 blocks = 1/CU, 512 threads. Block = 128 batch rows (bm) x 128 gate cols
// (bn); h exchange is same-XCD L2-local. D = W x h (swapped operands): lane's
// acc[qm][qn] = (i,f,g,o) of one (batch,unit) -> cell in registers. W: kt{x,0,1}
// in 96 VGPRs, kt2..7 persistent LDS. 2 waves/SIMD so VALU/ds_read/stall of one
// wave hides under the other's MFMA — the TLP r11 lacked.
__global__ __launch_bounds__(512, 2) void k_persist(
    const u16* __restrict__ xb, const u16* __restrict__ Wp,
    const float* __restrict__ bp, const float* __restrict__ c0,
    u16* __restrict__ hs, float* __restrict__ foutH, float* __restrict__ foutC,
    unsigned* __restrict__ flags)
{
    extern __shared__ char smem[];
    char* Wlds = smem + WLDS_OFF;
    char* ring = smem + RING_OFF;
    u16*  hpk  = (u16*)(smem + HPK_OFF);

    const int tid = threadIdx.x;
    const int lane = tid & 63;
    const int w = tid >> 6;                     // 0..7
    const int wm = w & 1, wn = w >> 1;          // wm: gate half, wn: batch quarter
    const int bm = blockIdx.x & 15, bn = blockIdx.x >> 4;
    const int m0 = bm * 128, n0 = bn * 128;
    const int rsub = lane >> 3;                 // staged row within 8-row chunk
    const int colsw = (((lane & 7) ^ rsub) << 3);   // pre-swizzled SRC granule (u16)
    const int bsub = lane & 15;
    const int usub = lane >> 4;                 // 0..3

    // ---- stage W K-tiles kt=2..7 into LDS (once) ----
#pragma unroll
    for (int t = 0; t < 6; ++t)
#pragma unroll
        for (int it = 0; it < 2; ++it) {
            int wc = w * 2 + it;                // 0..15
            gld16(Wp + (size_t)(n0 + wc * 8 + rsub) * KP + (t + 2) * 64 + colsw,
                  Wlds + t * 16384 + wc * 1024);
        }

    // ---- W reg tiles: {x(k=512..575), kt0, kt1} = 24 short8 = 96 VGPR ----
    short8 wreg[3][2][4];
#pragma unroll
    for (int t = 0; t < 3; ++t) {
        const int koff = (t == 0) ? 512 : (t - 1) * 64;
#pragma unroll
        for (int kk = 0; kk < 2; ++kk)
#pragma unroll
            for (int qm = 0; qm < 4; ++qm)
                wreg[t][kk][qm] = *(const short8*)(
                    Wp + (size_t)(n0 + wm * 64 + qm * 16 + bsub) * KP
                       + koff + kk * 32 + usub * 8);
    }

    // ---- bias (i,f,g,o per unit) + resident c-state (8 cells/thread) ----
    float4 bb[4];
#pragma unroll
    for (int qm = 0; qm < 4; ++qm)
        bb[qm] = *(const float4*)(bp + n0 + wm * 64 + qm * 16 + usub * 4);
    float c[4][2];
#pragma unroll
    for (int qm = 0; qm < 4; ++qm)
#pragma unroll
        for (int qn = 0; qn < 2; ++qn)
            c[qm][qn] = c0[(size_t)(m0 + wn * 32 + qn * 16 + bsub) * HID
                           + (n0 >> 2) + wm * 16 + qm * 4 + usub];

    WAITV(0);
    __syncthreads();                            // Wlds ready for all waves

#pragma unroll 1
    for (int l = 0; l < LSEQ; ++l) {
        const u16* hsrc = hs + (size_t)l * BH;

        // stage x-tile -> slot0 (issued before the spin; drained at syncthreads)
        {
            const u16* xs = xb + (size_t)l * BATCH * 64;
#pragma unroll
            for (int it = 0; it < 2; ++it) {
                int wc = w * 2 + it;
                gld16(xs + (size_t)(m0 + wc * 8 + rsub) * 64 + colsw, ring + wc * 1024);
            }
        }
        if (l > 0 && w == 0) {                  // wait step-(l-1) producers of row bm
            const unsigned* f = flags + (unsigned)(l - 1) * 256 + bm * 16;
            for (;;) {
                unsigned v = (lane < 16)
                    ? __hip_atomic_load(f + lane, __ATOMIC_RELAXED, __HIP_MEMORY_SCOPE_AGENT)
                    : 1u;
                if (__all(v != 0)) break;
                __builtin_amdgcn_s_sleep(2);
            }
        }
        __syncthreads();
        __builtin_amdgcn_sched_barrier(0);

        // stage h kt=0 -> slot1
#pragma unroll
        for (int it = 0; it < 2; ++it) {
            int wc = w * 2 + it;
            gld16(hsrc + (size_t)(m0 + wc * 8 + rsub) * HID + colsw,
                  ring + 16384 + wc * 1024);
        }

        f32x4 acc[4][2] = {};
        // ring-3: {vmcnt(2); barrier; stage t(i+2); compute t(i)}
#pragma unroll
        for (int i = 0; i < 9; ++i) {
            if (i > 0) {
                if (i < 8) WAITV(2); else WAITV(0);
                __builtin_amdgcn_s_barrier();
                __builtin_amdgcn_sched_barrier(0);
            }
            if (i + 2 <= 8) {                   // stage tile i+2 = h kt=i+1
                char* dst = ring + ((i + 2) % 3) * 16384;
#pragma unroll
                for (int it = 0; it < 2; ++it) {
                    int wc = w * 2 + it;
                    gld16(hsrc + (size_t)(m0 + wc * 8 + rsub) * HID + (i + 1) * 64 + colsw,
                          dst + wc * 1024);
                }
            }
            const u16* Bs_ = (const u16*)(ring + (i % 3) * 16384);
#pragma unroll
            for (int kk = 0; kk < 2; ++kk) {
                short8 hv[2];
#pragma unroll
                for (int qn = 0; qn < 2; ++qn)
                    hv[qn] = *(const short8*)(Bs_ + (wn * 32 + qn * 16 + bsub) * 64
                                 + (((kk * 4 + usub) ^ (lane & 7)) << 3));
                short8 wf[4];
                if (i <= 2) {                   // reg tiles: i=0 x, i=1 kt0, i=2 kt1
#pragma unroll
                    for (int qm = 0; qm < 4; ++qm) wf[qm] = wreg[i][kk][qm];
                } else {                        // LDS tiles: kt=i-1 in [2,7] -> tile i-3
                    const u16* Ws_ = (const u16*)(Wlds + (i - 3) * 16384);
#pragma unroll
                    for (int qm = 0; qm < 4; ++qm)
                        wf[qm] = *(const short8*)(Ws_ + (wm * 64 + qm * 16 + bsub) * 64
                                     + (((kk * 4 + usub) ^ (lane & 7)) << 3));
                }
#pragma unroll
                for (int qm = 0; qm < 4; ++qm)
#pragma unroll
                    for (int qn = 0; qn < 2; ++qn)
                        acc[qm][qn] = __builtin_amdgcn_mfma_f32_16x16x32_bf16(
                            wf[qm], hv[qn], acc[qm][qn], 0, 0, 0);
            }
        }

        // cell fully in-register: acc[qm][qn] = (i,f,g,o) of (batch b, unit u)
        const bool last = (l == LSEQ - 1);
#pragma unroll
        for (int qm = 0; qm < 4; ++qm) {
            const float4 b4 = bb[qm];
            const int u_loc = wm * 16 + qm * 4 + usub;
#pragma unroll
            for (int qn = 0; qn < 2; ++qn) {
                const int b_loc = wn * 32 + qn * 16 + bsub;
                float gi = acc[qm][qn][0] + b4.x;
                float gf = acc[qm][qn][1] + b4.y;
                float gg = acc[qm][qn][2] + b4.z;
                float go = acc[qm][qn][3] + b4.w;
                float cn = sig_(gf) * c[qm][qn] + sig_(gi) * th_(gg);
                float hn = sig_(go) * th_(cn);
                c[qm][qn] = cn;
                hpk[b_loc * 32 + (u_loc ^ ((b_loc & 7) << 2))] = f2bf(hn);
                if (last) {
                    size_t ci = (size_t)(m0 + b_loc) * HID + (n0 >> 2) + u_loc;
                    foutH[ci] = hn; foutC[ci] = cn;
                }
            }
        }
        __syncthreads();                        // hpack complete (ring reads done)

        // coalesced h store: thread -> 16B of hs[l+1] (same-XCD L2 exchange)
        {
            const int b = tid >> 2, seg = tid & 3;
            unsigned long long q[2];
#pragma unroll
            for (int g = 0; g < 2; ++g) {
                int G = seg * 2 + g;
                int gs = G ^ (b & 7);
                q[g] = *(const unsigned long long*)((const char*)hpk + b * 64 + gs * 8);
            }
            u16* dst = hs + (size_t)(l + 1) * BH + (size_t)(m0 + b) * HID
                       + (n0 >> 2) + seg * 8;
            *(uint4*)(dst) = make_uint4((unsigned)q[0], (unsigned)(q[0] >> 32),
                                        (unsigned)q[1], (unsigned)(q[1] >> 32));
        }
        WAITV(0);                               // h (and last-step fout) stores in L2
        __syncthreads();                        // every wave's stores drained
        if (tid == 0)
            __hip_atomic_store(flags + (unsigned)l * 256 + bm * 16 + bn, 1u,
                               __ATOMIC_RELAXED, __HIP_MEMORY_SCOPE_AGENT);
    }
}

// ---------------- output projection: (L*B, 512) x (96, 512)^T ----------------
__global__ __launch_bounds__(256) void k_scores(
    const u16* __restrict__ hsall, const u16* __restrict__ Wb,
    const float* __restrict__ bo, float* __restrict__ out)
{
    __shared__ char smem[28672];
    u16* As = (u16*)smem;               // [128][64]
    u16* Bs = (u16*)(smem + 16384);     // [96][64]
    const int tid = threadIdx.x, lane = tid & 63, w = tid >> 6;
    const size_t m0 = (size_t)blockIdx.x * 128;
    const int colo = (lane & 7) * 8;
    const int rsub = lane >> 3;
    f32x4 acc[2][6] = {};

    for (int kt = 0; kt < 8; ++kt) {
#pragma unroll
        for (int it = 0; it < 4; ++it) {
            int wc = w * 4 + it;
            int r = wc * 8 + rsub;
            gld16(hsall + (m0 + r) * 512 + kt * 64 + colo, smem + wc * 1024);
        }
#pragma unroll
        for (int it = 0; it < 3; ++it) {
            int wc = w * 3 + it;                  // 0..11
            int r = wc * 8 + rsub;                // 0..95
            gld16(Wb + (size_t)r * 512 + kt * 64 + colo, smem + 16384 + wc * 1024);
        }
        __syncthreads();
#pragma unroll
        for (int kk = 0; kk < 2; ++kk) {
            short8 av[2], bv[6];
#pragma unroll
            for (int i = 0; i < 2; ++i)
                av[i] = *(const short8*)(As + (w * 32 + i * 16 + (lane & 15)) * 64 + kk * 32 + (lane >> 4) * 8);
#pragma unroll
            for (int j = 0; j < 6; ++j)
                bv[j] = *(const short8*)(Bs + (j * 16 + (lane & 15)) * 64 + kk * 32 + (lane >> 4) * 8);
#pragma unroll
            for (int i = 0; i < 2; ++i)
#pragma unroll
                for (int j = 0; j < 6; ++j)
                    acc[i][j] = __builtin_amdgcn_mfma_f32_16x16x32_bf16(av[i], bv[j], acc[i][j], 0, 0, 0);
        }
        __syncthreads();
    }
#pragma unroll
    for (int i = 0; i < 2; ++i) {
        int ml = w * 32 + i * 16 + (lane >> 4) * 4;
#pragma unroll
        for (int j = 0; j < 6; ++j) {
            int v = j * 16 + (lane & 15);
            float bbv = bo[v];
#pragma unroll
            for (int r = 0; r < 4; ++r)
                out[(m0 + ml + r) * 96 + v] = acc[i][j][r] + bbv;
        }
    }
}

// ---------------- launcher ----------------
extern "C" void kernel_launch(void* const* d_in, const int* in_sizes, int n_in,
                              void* d_out, int out_size, void* d_ws, size_t ws_size,
                              hipStream_t stream) {
    const int*   ids  = (const int*)d_in[0];
    const float* h0   = (const float*)d_in[1];
    const float* c0   = (const float*)d_in[2];
    const float* emb  = (const float*)d_in[3];
    const float* Wih  = (const float*)d_in[4];
    const float* Whh  = (const float*)d_in[5];
    const float* bih  = (const float*)d_in[6];
    const float* bhh  = (const float*)d_in[7];
    const float* Wout = (const float*)d_in[8];
    const float* bout = (const float*)d_in[9];

    char* ws = (char*)d_ws;
    u16*      hs    = (u16*)ws;                       // 65*BH*2 = 136,314,880
    unsigned* flags = (unsigned*)(ws + 136314880);    // 64*256*4
    u16*      xb    = (u16*)(ws + 140509184);         // L*B*64*2
    u16*      Wp    = (u16*)(ws + 157286400);         // 2048*576*2
    float*    bp    = (float*)(ws + 159645696);       // 2048*4
    u16*      Wb    = (u16*)(ws + 159653888);         // 96*512*2
    float*    out   = (float*)d_out;

    k_init<<<dim3(BH / 256), dim3(256), 0, stream>>>(h0, hs, flags);
    k_pack_w<<<dim3(NG * 72 / 256), dim3(256), 0, stream>>>(Wih, Whh, bih, bhh, Wp, bp);
    k_embed<<<dim3(LSEQ * BATCH * 8 / 256), dim3(256), 0, stream>>>(ids, emb, xb);
    k_pack_wout<<<dim3(VOCAB * HID / 8 / 256), dim3(256), 0, stream>>>(Wout, Wb);

    hipFuncSetAttribute((const void*)k_persist,
                        hipFuncAttributeMaxDynamicSharedMemorySize, SMEM_TOT);
    k_persist<<<dim3(256), dim3(512), SMEM_TOT, stream>>>(
        xb, Wp, bp, c0, hs, out + 12582912, out + 12582912 + BH, flags);

    k_scores<<<dim3(LSEQ * BATCH / 128), dim3(256), 0, stream>>>(hs + BH, Wb, bout, out);
}